// Round 16
// baseline (263.497 us; speedup 1.0000x reference)
//
#include <hip/hip_runtime.h>
#include <cstdint>

// MambaBlock: out = (silu(x@in_w[:1024]^T+b0) * silu(x@in_w[1024:]^T+b1)) @ out_w^T + out_b
// M = 32768, K = 1024. dt_w/dt_b/A/Dp are dead inputs.
//
// Round 16 = r15 (252.8 us) + counted-lgkm gates: per K-tile issue all 12
// ds_reads (slice0 | sched_barrier | slice1) + 4 stage gloads, ONE barrier,
// then {lgkmcnt(6) -> 8 MFMA slice0} {lgkmcnt(0) -> 8 MFMA slice1}. LDS
// completes in-order, so lgkmcnt(6) = slice0 ready; slice1 reads stream under
// slice0's MFMAs (within-wave overlap, on top of r15's cross-wave). Barriers
// 3 -> 2 per K-tile. sched_barrier(0) after each waitcnt (rule #18). vmcnt
// ledger identical to r11/r15: enter tile with 8 outstanding, WAITB(4)
// retires stage(t), stage(t+2) issued in-body.
// Core: 256x256 tile, BK=32, 8 waves 2Mx4N, 3 LDS bufs (96 KiB, 1 block/CU),
// 32x32x16 MFMA, swizzle key2(row)=((row>>1)^(row>>4))&3 (0 conflicts),
// setprio, bijective XCD swizzle, shuffle-free paired-silu epilogue,
// merged single-launch casts.
// Ledger: r5 32x32 +17%; r6 swizzle +4%; r15 phase-gate +6%; r7 spill; r8
// clamp-spill; r10 cast-fusion -71us; r12 occupancy register-pinned; r13
// B-direct -71us.

typedef __bf16 bf16x8 __attribute__((ext_vector_type(8)));
typedef float f32x16 __attribute__((ext_vector_type(16)));

#define KD 1024
#define BUF_ELEMS 16384  // (256*32 A + 256*32 B) elems per buffer

__device__ __forceinline__ void gload_lds16(const void* g, void* lds_u) {
  __builtin_amdgcn_global_load_lds(
      (__attribute__((address_space(1))) void*)(uintptr_t)g,
      (__attribute__((address_space(3))) void*)(uint32_t)(uintptr_t)lds_u,
      16, 0, 0);
}

#define WAITB(N) do { \
  asm volatile("s_waitcnt vmcnt(" #N ")" ::: "memory"); \
  asm volatile("s_barrier" ::: "memory"); } while (0)

// ---------------- merged cast kernel (single launch) ----------------
// blocks [0, 16384): x -> xb; [16384, 17408): in_w -> w1b (blk32 interleave);
// [17408, 17920): out_w -> w2b
__global__ void cast_all(const float* __restrict__ x, __bf16* __restrict__ xb,
                         const float* __restrict__ in_w, __bf16* __restrict__ w1b,
                         const float* __restrict__ out_w, __bf16* __restrict__ w2b) {
  const int b = blockIdx.x;
  if (b < 16384) {
    int i = b * 256 + threadIdx.x;  // < 4194304 = 33554432/8
    const float4* p = (const float4*)x;
    float4 v0 = p[2 * i];
    float4 v1 = p[2 * i + 1];
    bf16x8 o;
    o[0] = (__bf16)v0.x; o[1] = (__bf16)v0.y; o[2] = (__bf16)v0.z; o[3] = (__bf16)v0.w;
    o[4] = (__bf16)v1.x; o[5] = (__bf16)v1.y; o[6] = (__bf16)v1.z; o[7] = (__bf16)v1.w;
    ((bf16x8*)xb)[i] = o;
  } else if (b < 17408) {
    // W1'' 32-row block interleave: out-row r, blk=r>>5, t=r&31:
    //   src row = (blk&1)*1024 + (blk>>1)*32 + t
    int i = (b - 16384) * 256 + threadIdx.x;  // 2048*128 threads
    int orow = i >> 7;
    int chunk = i & 127;
    int bb = orow >> 5, t = orow & 31;
    int srow = (bb & 1) * 1024 + (bb >> 1) * 32 + t;
    const float4* p = (const float4*)(in_w + ((size_t)srow << 10) + (chunk << 3));
    float4 v0 = p[0], v1 = p[1];
    bf16x8 o;
    o[0] = (__bf16)v0.x; o[1] = (__bf16)v0.y; o[2] = (__bf16)v0.z; o[3] = (__bf16)v0.w;
    o[4] = (__bf16)v1.x; o[5] = (__bf16)v1.y; o[6] = (__bf16)v1.z; o[7] = (__bf16)v1.w;
    *(bf16x8*)(w1b + ((size_t)orow << 10) + (chunk << 3)) = o;
  } else {
    int i = (b - 17408) * 256 + threadIdx.x;  // < 131072 = 1048576/8
    const float4* p = (const float4*)out_w;
    float4 v0 = p[2 * i];
    float4 v1 = p[2 * i + 1];
    bf16x8 o;
    o[0] = (__bf16)v0.x; o[1] = (__bf16)v0.y; o[2] = (__bf16)v0.z; o[3] = (__bf16)v0.w;
    o[4] = (__bf16)v1.x; o[5] = (__bf16)v1.y; o[6] = (__bf16)v1.z; o[7] = (__bf16)v1.w;
    ((bf16x8*)w2b)[i] = o;
  }
}

// ---------------- GEMM core ----------------
// Prologue staging of one full K-tile (4 gloads).
template <int BUF>
__device__ __forceinline__ void stage_tile(const __bf16*& pa, const __bf16*& pb,
                                           __bf16* smw) {
  __bf16* d = smw + BUF * BUF_ELEMS;
  gload_lds16(pa, d);
  gload_lds16(pa + 128 * KD, d + 4096);
  gload_lds16(pb, d + 8192);
  gload_lds16(pb + 128 * KD, d + 12288);
  pa += 32;
  pb += 32;
}

// One K-tile from buffer BUF with counted-lgkm gates; stages tile t+2 into
// SBUF when DO_STAGE. Issue order (pinned): slice0 reads | slice1 reads |
// stage gloads | barrier | lgkm(6) MFMA0 | lgkm(0) MFMA1.
template <int BUF, int SBUF, bool DO_STAGE>
__device__ __forceinline__ void compute_tile(const __bf16* sm,
                                             int aRow, int bRow,
                                             int o0, int o1,
                                             const __bf16*& pa, const __bf16*& pb,
                                             __bf16* smw,
                                             f32x16 (&acc)[4][2]) {
  const __bf16* base = sm + BUF * BUF_ELEMS;
  __bf16* d = smw + SBUF * BUF_ELEMS;
  bf16x8 a0[4], a1[4], b0[2], b1[2];
  // ---- slice 0 reads (6 ds_read_b128) ----
  b0[0] = *(const bf16x8*)(base + bRow + o0);
  b0[1] = *(const bf16x8*)(base + bRow + 1024 + o1);
#pragma unroll
  for (int i = 0; i < 4; ++i)
    a0[i] = *(const bf16x8*)(base + aRow + i * 1024 + ((i & 1) ? o1 : o0));
  __builtin_amdgcn_sched_barrier(0);  // pin: slice0 issues before slice1
  // ---- slice 1 reads (6 ds_read_b128) ----
  b1[0] = *(const bf16x8*)(base + bRow + o1);
  b1[1] = *(const bf16x8*)(base + bRow + 1024 + o0);
#pragma unroll
  for (int i = 0; i < 4; ++i)
    a1[i] = *(const bf16x8*)(base + aRow + i * 1024 + ((i & 1) ? o0 : o1));
  if (DO_STAGE) {
    gload_lds16(pa, d);
    gload_lds16(pa + 128 * KD, d + 4096);
    gload_lds16(pb, d + 8192);
    gload_lds16(pb + 128 * KD, d + 12288);
    pa += 32;
    pb += 32;
  }
  // ---- single clustering barrier, then counted-lgkm gates ----
  __builtin_amdgcn_s_barrier();
  asm volatile("s_waitcnt lgkmcnt(6)" ::: "memory");  // slice0 ready (in-order)
  __builtin_amdgcn_sched_barrier(0);
  __builtin_amdgcn_s_setprio(1);
#pragma unroll
  for (int i = 0; i < 4; ++i)
#pragma unroll
    for (int j = 0; j < 2; ++j)
      acc[i][j] = __builtin_amdgcn_mfma_f32_32x32x16_bf16(a0[i], b0[j], acc[i][j], 0, 0, 0);
  __builtin_amdgcn_s_setprio(0);
  asm volatile("s_waitcnt lgkmcnt(0)" ::: "memory");  // slice1 ready
  __builtin_amdgcn_sched_barrier(0);
  __builtin_amdgcn_s_setprio(1);
#pragma unroll
  for (int i = 0; i < 4; ++i)
#pragma unroll
    for (int j = 0; j < 2; ++j)
      acc[i][j] = __builtin_amdgcn_mfma_f32_32x32x16_bf16(a1[i], b1[j], acc[i][j], 0, 0, 0);
  __builtin_amdgcn_s_setprio(0);
}

// Fills acc for the 256x256 tile at (m0, n0). A:[M][1024], B:[Nrows][1024].
__device__ __forceinline__ void gemm_core(const __bf16* __restrict__ A,
                                          const __bf16* __restrict__ B,
                                          __bf16* sm, long m0, long n0,
                                          f32x16 (&acc)[4][2]) {
  const int t = threadIdx.x;
  const int w = t >> 6;
  const int lane = t & 63;
  const int c31 = lane & 31;
  const int hi = lane >> 5;
  const int wr = w >> 2;  // 0..1 (M)
  const int wc = w & 3;   // 0..3 (N)

  // staging source: lane l covers LDS row w*16+(l>>2), phys slot l&3, which
  // must hold logical chunk (l&3) ^ key2(row); key2 = ((l>>3)&3) ^ (w&3).
  const int l = lane;
  const int stg_row = w * 16 + (l >> 2);
  const int stg_col = ((l & 3) ^ ((l >> 3) & 3) ^ (w & 3)) << 3;
  const __bf16* pa = A + (m0 + stg_row) * KD + stg_col;
  const __bf16* pb = B + (n0 + stg_row) * KD + stg_col;
  __bf16* smw = sm + w * 512;  // wave-uniform LDS base (1024B per wave-instr)

  // fragment read offsets. key_base = ((c31>>1)&3) ^ ((c31>>4)&1); frag idx
  // parity flips key by 2 (row bit 5 via r>>4). o1 = o0 ^ 16 elems.
  const int key_base = ((c31 >> 1) & 3) ^ ((c31 >> 4) & 1);
  const int o0 = (hi ^ key_base) << 3;
  const int o1 = o0 ^ 16;
  const int aRow = (wr * 128 + c31) * 32;          // + i*1024
  const int bRow = 8192 + (wc * 64 + c31) * 32;    // + j*1024

#pragma unroll
  for (int i = 0; i < 4; ++i)
#pragma unroll
    for (int j = 0; j < 2; ++j)
      acc[i][j] = (f32x16){0.f, 0.f, 0.f, 0.f, 0.f, 0.f, 0.f, 0.f,
                           0.f, 0.f, 0.f, 0.f, 0.f, 0.f, 0.f, 0.f};

  // prologue: stage tiles 0,1 (outstanding = 8)
  stage_tile<0>(pa, pb, smw);
  stage_tile<1>(pa, pb, smw);

  // tiles 0..29: tile-top WAITB(4) retires stage(t); body stages tile t+2
  // into buf (t+2)%3 -> outstanding back to 8.
  for (int it = 0; it < 10; ++it) {
    WAITB(4);
    compute_tile<0, 2, true>(sm, aRow, bRow, o0, o1, pa, pb, smw, acc);
    WAITB(4);
    compute_tile<1, 0, true>(sm, aRow, bRow, o0, o1, pa, pb, smw, acc);
    WAITB(4);
    compute_tile<2, 1, true>(sm, aRow, bRow, o0, o1, pa, pb, smw, acc);
  }
  // tail: tiles 30 (buf0), 31 (buf1), no staging
  WAITB(4);
  compute_tile<0, 2, false>(sm, aRow, bRow, o0, o1, pa, pb, smw, acc);
  WAITB(0);
  compute_tile<1, 2, false>(sm, aRow, bRow, o0, o1, pa, pb, smw, acc);
}

// ---------------- GEMM1: Y = X @ W1''^T, paired-silu epilogue -> G bf16 -----
__global__ __launch_bounds__(512, 2)
void gemm1_silu(const __bf16* __restrict__ X, const __bf16* __restrict__ W1i,
                const float* __restrict__ in_b, __bf16* __restrict__ G) {
  __shared__ __bf16 sm[3 * BUF_ELEMS];
  // XCD-aware bijective swizzle: nwg = 128*8 = 1024, divisible by 8
  const int bid = blockIdx.x;
  const int swz = (bid & 7) * 128 + (bid >> 3);
  const long m0 = (long)(swz >> 3) * 256;
  const long n0 = (long)(swz & 7) * 256;

  f32x16 acc[4][2];
  gemm_core(X, W1i, sm, m0, n0, acc);

  const int lane = threadIdx.x & 63;
  const int w = threadIdx.x >> 6;
  const int wr = w >> 2, wc = w & 3;
  const int c31 = lane & 31;
  const int hi = lane >> 5;

  // G column for this wave's frag pair: even block j=0 (x_val), odd j=1 (res)
  const int gc = ((int)n0 >> 1) + wc * 32 + c31;
  const float bx = in_b[gc];
  const float br = in_b[1024 + gc];

#pragma unroll
  for (int i = 0; i < 4; ++i)
#pragma unroll
    for (int reg = 0; reg < 16; ++reg) {
      const int row = wr * 128 + i * 32 + (reg & 3) + 8 * (reg >> 2) + 4 * hi;
      float xv = acc[i][0][reg] + bx;
      float rs = acc[i][1][reg] + br;
      float e1 = __expf(-xv);
      float e2 = __expf(-rs);
      float g = xv * rs * __builtin_amdgcn_rcpf((1.0f + e1) * (1.0f + e2));
      G[(m0 + row) * 1024 + gc] = (__bf16)g;
    }
}

// ---------------- GEMM2: OUT = G @ W2^T + out_b (fp32) ----------------
__global__ __launch_bounds__(512, 2)
void gemm2_bias(const __bf16* __restrict__ G, const __bf16* __restrict__ W2,
                const float* __restrict__ out_b, float* __restrict__ OUT) {
  __shared__ __bf16 sm[3 * BUF_ELEMS];
  // nwg = 128*4 = 512, divisible by 8
  const int bid = blockIdx.x;
  const int swz = (bid & 7) * 64 + (bid >> 3);
  const long m0 = (long)(swz >> 2) * 256;
  const long n0 = (long)(swz & 3) * 256;

  f32x16 acc[4][2];
  gemm_core(G, W2, sm, m0, n0, acc);

  const int lane = threadIdx.x & 63;
  const int w = threadIdx.x >> 6;
  const int wr = w >> 2, wc = w & 3;
  const int c31 = lane & 31;
  const int hi = lane >> 5;

  float ob[2];
#pragma unroll
  for (int j = 0; j < 2; ++j)
    ob[j] = out_b[(int)n0 + wc * 64 + j * 32 + c31];
#pragma unroll
  for (int i = 0; i < 4; ++i)
#pragma unroll
    for (int j = 0; j < 2; ++j)
#pragma unroll
      for (int reg = 0; reg < 16; ++reg) {
        const int row = wr * 128 + i * 32 + (reg & 3) + 8 * (reg >> 2) + 4 * hi;
        const int col = (int)n0 + wc * 64 + j * 32 + c31;
        OUT[(m0 + row) * 1024 + col] = acc[i][j][reg] + ob[j];
      }
}

extern "C" void kernel_launch(void* const* d_in, const int* in_sizes, int n_in,
                              void* d_out, int out_size, void* d_ws, size_t ws_size,
                              hipStream_t stream) {
  const float* x = (const float*)d_in[0];
  const float* in_w = (const float*)d_in[1];
  const float* in_b = (const float*)d_in[2];
  const float* out_w = (const float*)d_in[3];
  const float* out_b = (const float*)d_in[4];
  // d_in[5..8] (dt_w, dt_b, A, Dp) are dead in the reference.

  char* ws = (char*)d_ws;
  __bf16* xb = (__bf16*)(ws);                       // 67108864 B
  __bf16* w1b = (__bf16*)(ws + (size_t)67108864);   //  4194304 B (blk32 interleaved)
  __bf16* w2b = (__bf16*)(ws + (size_t)71303168);   //  2097152 B
  __bf16* gb = (__bf16*)(ws + (size_t)73400320);    // 67108864 B

  cast_all<<<dim3(17920), 256, 0, stream>>>(x, xb, in_w, w1b, out_w, w2b);
  gemm1_silu<<<dim3(1024), 512, 0, stream>>>(xb, w1b, in_b, gb);
  gemm2_bias<<<dim3(512), 512, 0, stream>>>(gb, w2b, out_b, (float*)d_out);
}

// Round 17
// 253.108 us; speedup vs baseline: 1.0410x; 1.0410x over previous
//
#include <hip/hip_runtime.h>
#include <cstdint>

// MambaBlock: out = (silu(x@in_w[:1024]^T+b0) * silu(x@in_w[1024:]^T+b1)) @ out_w^T + out_b
// M = 32768, K = 1024. dt_w/dt_b/A/Dp are dead inputs.
//
// FINAL (round 17) = round 15 verified optimum (252.8 us), restored after
// r16's counted-lgkm regression (slice1 frags live across slice0 MFMAs ->
// +12 VGPR longer dep chains; single barrier/tile lost cross-wave phase
// alignment -> -4%).
// Structure: per K-tile two phases {6 ds_read (k-slice) + 2 stage gloads ->
// barrier -> lgkmcnt(0)+sched_barrier -> setprio(1) -> 8 MFMA -> setprio(0)}.
// Core: 256x256 tile, BK=32, 8 waves 2Mx4N, 3 LDS bufs (96 KiB, 1 block/CU),
// tile-top WAITB(4) counted (never 0 in main loop), 32x32x16 MFMA, swizzle
// key2(row)=((row>>1)^(row>>4))&3 both sides (0 conflicts), bijective XCD
// swizzle, shuffle-free paired-silu epilogue (blk32 W1), merged casts.
// Ledger (all measured): r3/r4 16x16 phase splits null; r5 32x32 +17%;
// r6 swizzle +4%; r15 phase-gate +6%; r16 lgkm-fuse -4%; r7 fat tile spill;
// r8 bounds clamp spill; r10 A-cast fusion -71us; r12 LDS-cut neutral
// (occupancy register-pinned: ~100 arch + 128 acc VGPR = 2 waves/SIMD);
// r13 B-direct -71us. GEMM1 = 1015 TF eff (41% dense peak).

typedef __bf16 bf16x8 __attribute__((ext_vector_type(8)));
typedef float f32x16 __attribute__((ext_vector_type(16)));

#define KD 1024
#define BUF_ELEMS 16384  // (256*32 A + 256*32 B) elems per buffer

__device__ __forceinline__ void gload_lds16(const void* g, void* lds_u) {
  __builtin_amdgcn_global_load_lds(
      (__attribute__((address_space(1))) void*)(uintptr_t)g,
      (__attribute__((address_space(3))) void*)(uint32_t)(uintptr_t)lds_u,
      16, 0, 0);
}

#define WAITB(N) do { \
  asm volatile("s_waitcnt vmcnt(" #N ")" ::: "memory"); \
  asm volatile("s_barrier" ::: "memory"); } while (0)

#define PH_GATE() do { \
  __builtin_amdgcn_s_barrier(); \
  asm volatile("s_waitcnt lgkmcnt(0)" ::: "memory"); \
  __builtin_amdgcn_sched_barrier(0); \
  __builtin_amdgcn_s_setprio(1); } while (0)

// ---------------- merged cast kernel (single launch) ----------------
// blocks [0, 16384): x -> xb; [16384, 17408): in_w -> w1b (blk32 interleave);
// [17408, 17920): out_w -> w2b
__global__ void cast_all(const float* __restrict__ x, __bf16* __restrict__ xb,
                         const float* __restrict__ in_w, __bf16* __restrict__ w1b,
                         const float* __restrict__ out_w, __bf16* __restrict__ w2b) {
  const int b = blockIdx.x;
  if (b < 16384) {
    int i = b * 256 + threadIdx.x;  // < 4194304 = 33554432/8
    const float4* p = (const float4*)x;
    float4 v0 = p[2 * i];
    float4 v1 = p[2 * i + 1];
    bf16x8 o;
    o[0] = (__bf16)v0.x; o[1] = (__bf16)v0.y; o[2] = (__bf16)v0.z; o[3] = (__bf16)v0.w;
    o[4] = (__bf16)v1.x; o[5] = (__bf16)v1.y; o[6] = (__bf16)v1.z; o[7] = (__bf16)v1.w;
    ((bf16x8*)xb)[i] = o;
  } else if (b < 17408) {
    // W1'' 32-row block interleave: out-row r, blk=r>>5, t=r&31:
    //   src row = (blk&1)*1024 + (blk>>1)*32 + t
    int i = (b - 16384) * 256 + threadIdx.x;  // 2048*128 threads
    int orow = i >> 7;
    int chunk = i & 127;
    int bb = orow >> 5, t = orow & 31;
    int srow = (bb & 1) * 1024 + (bb >> 1) * 32 + t;
    const float4* p = (const float4*)(in_w + ((size_t)srow << 10) + (chunk << 3));
    float4 v0 = p[0], v1 = p[1];
    bf16x8 o;
    o[0] = (__bf16)v0.x; o[1] = (__bf16)v0.y; o[2] = (__bf16)v0.z; o[3] = (__bf16)v0.w;
    o[4] = (__bf16)v1.x; o[5] = (__bf16)v1.y; o[6] = (__bf16)v1.z; o[7] = (__bf16)v1.w;
    *(bf16x8*)(w1b + ((size_t)orow << 10) + (chunk << 3)) = o;
  } else {
    int i = (b - 17408) * 256 + threadIdx.x;  // < 131072 = 1048576/8
    const float4* p = (const float4*)out_w;
    float4 v0 = p[2 * i];
    float4 v1 = p[2 * i + 1];
    bf16x8 o;
    o[0] = (__bf16)v0.x; o[1] = (__bf16)v0.y; o[2] = (__bf16)v0.z; o[3] = (__bf16)v0.w;
    o[4] = (__bf16)v1.x; o[5] = (__bf16)v1.y; o[6] = (__bf16)v1.z; o[7] = (__bf16)v1.w;
    ((bf16x8*)w2b)[i] = o;
  }
}

// ---------------- GEMM core ----------------
// Phase-split compute of one K-tile from buffer BUF, staging tile t+2's
// A-half (phase 1) and B-half (phase 2) into buffer SBUF when DO_STAGE.
// k-slice 0 reads chunk o0 (i even) / o1 (i odd); k-slice 1 swapped.
template <int BUF, int SBUF, bool DO_STAGE>
__device__ __forceinline__ void compute_tile(const __bf16* sm,
                                             int aRow, int bRow,
                                             int o0, int o1,
                                             const __bf16*& pa, const __bf16*& pb,
                                             __bf16* smw,
                                             f32x16 (&acc)[4][2]) {
  const __bf16* base = sm + BUF * BUF_ELEMS;
  __bf16* d = smw + SBUF * BUF_ELEMS;
  // ---- phase 1: k-slice 0 (6 ds_read) + stage A pair ----
  bf16x8 a0[4], b0[2];
  b0[0] = *(const bf16x8*)(base + bRow + o0);
  b0[1] = *(const bf16x8*)(base + bRow + 1024 + o1);
#pragma unroll
  for (int i = 0; i < 4; ++i)
    a0[i] = *(const bf16x8*)(base + aRow + i * 1024 + ((i & 1) ? o1 : o0));
  if (DO_STAGE) {
    gload_lds16(pa, d);
    gload_lds16(pa + 128 * KD, d + 4096);
    pa += 32;
  }
  PH_GATE();
#pragma unroll
  for (int i = 0; i < 4; ++i)
#pragma unroll
    for (int j = 0; j < 2; ++j)
      acc[i][j] = __builtin_amdgcn_mfma_f32_32x32x16_bf16(a0[i], b0[j], acc[i][j], 0, 0, 0);
  __builtin_amdgcn_s_setprio(0);
  // ---- phase 2: k-slice 1 (6 ds_read) + stage B pair ----
  bf16x8 a1[4], b1[2];
  b1[0] = *(const bf16x8*)(base + bRow + o1);
  b1[1] = *(const bf16x8*)(base + bRow + 1024 + o0);
#pragma unroll
  for (int i = 0; i < 4; ++i)
    a1[i] = *(const bf16x8*)(base + aRow + i * 1024 + ((i & 1) ? o0 : o1));
  if (DO_STAGE) {
    gload_lds16(pb, d + 8192);
    gload_lds16(pb + 128 * KD, d + 12288);
    pb += 32;
  }
  PH_GATE();
#pragma unroll
  for (int i = 0; i < 4; ++i)
#pragma unroll
    for (int j = 0; j < 2; ++j)
      acc[i][j] = __builtin_amdgcn_mfma_f32_32x32x16_bf16(a1[i], b1[j], acc[i][j], 0, 0, 0);
  __builtin_amdgcn_s_setprio(0);
}

// Prologue staging of one full K-tile (4 gloads).
template <int BUF>
__device__ __forceinline__ void stage_tile(const __bf16*& pa, const __bf16*& pb,
                                           __bf16* smw) {
  __bf16* d = smw + BUF * BUF_ELEMS;
  gload_lds16(pa, d);
  gload_lds16(pa + 128 * KD, d + 4096);
  gload_lds16(pb, d + 8192);
  gload_lds16(pb + 128 * KD, d + 12288);
  pa += 32;
  pb += 32;
}

// Fills acc for the 256x256 tile at (m0, n0). A:[M][1024], B:[Nrows][1024].
__device__ __forceinline__ void gemm_core(const __bf16* __restrict__ A,
                                          const __bf16* __restrict__ B,
                                          __bf16* sm, long m0, long n0,
                                          f32x16 (&acc)[4][2]) {
  const int t = threadIdx.x;
  const int w = t >> 6;
  const int lane = t & 63;
  const int c31 = lane & 31;
  const int hi = lane >> 5;
  const int wr = w >> 2;  // 0..1 (M)
  const int wc = w & 3;   // 0..3 (N)

  // staging source: lane l covers LDS row w*16+(l>>2), phys slot l&3, which
  // must hold logical chunk (l&3) ^ key2(row); key2 = ((l>>3)&3) ^ (w&3).
  const int l = lane;
  const int stg_row = w * 16 + (l >> 2);
  const int stg_col = ((l & 3) ^ ((l >> 3) & 3) ^ (w & 3)) << 3;
  const __bf16* pa = A + (m0 + stg_row) * KD + stg_col;
  const __bf16* pb = B + (n0 + stg_row) * KD + stg_col;
  __bf16* smw = sm + w * 512;  // wave-uniform LDS base (1024B per wave-instr)

  // fragment read offsets. key_base = ((c31>>1)&3) ^ ((c31>>4)&1); frag idx
  // parity flips key by 2 (row bit 5 via r>>4). o1 = o0 ^ 16 elems.
  const int key_base = ((c31 >> 1) & 3) ^ ((c31 >> 4) & 1);
  const int o0 = (hi ^ key_base) << 3;
  const int o1 = o0 ^ 16;
  const int aRow = (wr * 128 + c31) * 32;          // + i*1024
  const int bRow = 8192 + (wc * 64 + c31) * 32;    // + j*1024

#pragma unroll
  for (int i = 0; i < 4; ++i)
#pragma unroll
    for (int j = 0; j < 2; ++j)
      acc[i][j] = (f32x16){0.f, 0.f, 0.f, 0.f, 0.f, 0.f, 0.f, 0.f,
                           0.f, 0.f, 0.f, 0.f, 0.f, 0.f, 0.f, 0.f};

  // prologue: stage tiles 0,1 (outstanding = 8)
  stage_tile<0>(pa, pb, smw);
  stage_tile<1>(pa, pb, smw);

  // tiles 0..29: tile-top WAITB(4) retires stage(t); phases stage tile t+2
  // into buf (t+2)%3 (A pair in ph1, B pair in ph2) -> outstanding back to 8.
  for (int it = 0; it < 10; ++it) {
    WAITB(4);
    compute_tile<0, 2, true>(sm, aRow, bRow, o0, o1, pa, pb, smw, acc);
    WAITB(4);
    compute_tile<1, 0, true>(sm, aRow, bRow, o0, o1, pa, pb, smw, acc);
    WAITB(4);
    compute_tile<2, 1, true>(sm, aRow, bRow, o0, o1, pa, pb, smw, acc);
  }
  // tail: tiles 30 (buf0), 31 (buf1), no staging
  WAITB(4);
  compute_tile<0, 2, false>(sm, aRow, bRow, o0, o1, pa, pb, smw, acc);
  WAITB(0);
  compute_tile<1, 2, false>(sm, aRow, bRow, o0, o1, pa, pb, smw, acc);
}

// ---------------- GEMM1: Y = X @ W1''^T, paired-silu epilogue -> G bf16 -----
__global__ __launch_bounds__(512, 2)
void gemm1_silu(const __bf16* __restrict__ X, const __bf16* __restrict__ W1i,
                const float* __restrict__ in_b, __bf16* __restrict__ G) {
  __shared__ __bf16 sm[3 * BUF_ELEMS];
  // XCD-aware bijective swizzle: nwg = 128*8 = 1024, divisible by 8
  const int bid = blockIdx.x;
  const int swz = (bid & 7) * 128 + (bid >> 3);
  const long m0 = (long)(swz >> 3) * 256;
  const long n0 = (long)(swz & 7) * 256;

  f32x16 acc[4][2];
  gemm_core(X, W1i, sm, m0, n0, acc);

  const int lane = threadIdx.x & 63;
  const int w = threadIdx.x >> 6;
  const int wr = w >> 2, wc = w & 3;
  const int c31 = lane & 31;
  const int hi = lane >> 5;

  // G column for this wave's frag pair: even block j=0 (x_val), odd j=1 (res)
  const int gc = ((int)n0 >> 1) + wc * 32 + c31;
  const float bx = in_b[gc];
  const float br = in_b[1024 + gc];

#pragma unroll
  for (int i = 0; i < 4; ++i)
#pragma unroll
    for (int reg = 0; reg < 16; ++reg) {
      const int row = wr * 128 + i * 32 + (reg & 3) + 8 * (reg >> 2) + 4 * hi;
      float xv = acc[i][0][reg] + bx;
      float rs = acc[i][1][reg] + br;
      float e1 = __expf(-xv);
      float e2 = __expf(-rs);
      float g = xv * rs * __builtin_amdgcn_rcpf((1.0f + e1) * (1.0f + e2));
      G[(m0 + row) * 1024 + gc] = (__bf16)g;
    }
}

// ---------------- GEMM2: OUT = G @ W2^T + out_b (fp32) ----------------
__global__ __launch_bounds__(512, 2)
void gemm2_bias(const __bf16* __restrict__ G, const __bf16* __restrict__ W2,
                const float* __restrict__ out_b, float* __restrict__ OUT) {
  __shared__ __bf16 sm[3 * BUF_ELEMS];
  // nwg = 128*4 = 512, divisible by 8
  const int bid = blockIdx.x;
  const int swz = (bid & 7) * 64 + (bid >> 3);
  const long m0 = (long)(swz >> 2) * 256;
  const long n0 = (long)(swz & 3) * 256;

  f32x16 acc[4][2];
  gemm_core(G, W2, sm, m0, n0, acc);

  const int lane = threadIdx.x & 63;
  const int w = threadIdx.x >> 6;
  const int wr = w >> 2, wc = w & 3;
  const int c31 = lane & 31;
  const int hi = lane >> 5;

  float ob[2];
#pragma unroll
  for (int j = 0; j < 2; ++j)
    ob[j] = out_b[(int)n0 + wc * 64 + j * 32 + c31];
#pragma unroll
  for (int i = 0; i < 4; ++i)
#pragma unroll
    for (int j = 0; j < 2; ++j)
#pragma unroll
      for (int reg = 0; reg < 16; ++reg) {
        const int row = wr * 128 + i * 32 + (reg & 3) + 8 * (reg >> 2) + 4 * hi;
        const int col = (int)n0 + wc * 64 + j * 32 + c31;
        OUT[(m0 + row) * 1024 + col] = acc[i][j][reg] + ob[j];
      }
}

extern "C" void kernel_launch(void* const* d_in, const int* in_sizes, int n_in,
                              void* d_out, int out_size, void* d_ws, size_t ws_size,
                              hipStream_t stream) {
  const float* x = (const float*)d_in[0];
  const float* in_w = (const float*)d_in[1];
  const float* in_b = (const float*)d_in[2];
  const float* out_w = (const float*)d_in[3];
  const float* out_b = (const float*)d_in[4];
  // d_in[5..8] (dt_w, dt_b, A, Dp) are dead in the reference.

  char* ws = (char*)d_ws;
  __bf16* xb = (__bf16*)(ws);                       // 67108864 B
  __bf16* w1b = (__bf16*)(ws + (size_t)67108864);   //  4194304 B (blk32 interleaved)
  __bf16* w2b = (__bf16*)(ws + (size_t)71303168);   //  2097152 B
  __bf16* gb = (__bf16*)(ws + (size_t)73400320);    // 67108864 B

  cast_all<<<dim3(17920), 256, 0, stream>>>(x, xb, in_w, w1b, out_w, w2b);
  gemm1_silu<<<dim3(1024), 512, 0, stream>>>(xb, w1b, in_b, gb);
  gemm2_bias<<<dim3(512), 512, 0, stream>>>(gb, w2b, out_b, (float*)d_out);
}